// Round 1
// baseline (465.783 us; speedup 1.0000x reference)
//
#include <hip/hip_runtime.h>

// ESN recurrence, MI355X — producer/consumer, LDS-traffic-minimized revision.
//
// THEORY (this round): the 490 µs version saturated the per-CU LDS pipe:
//  (a) producers re-read W[r] from LDS per item (2x ds_read_b128 at 32B lane
//      stride = 8-way bank conflict, ~9K LDS-cycles/phase),
//  (b) consumer's u reads were 32B-stride b128 (16 banks, ~16-way),
//  (c) the consumer's shfl (ds_bpermute) shares the same pipe and queues
//      behind all of it.
// Fixes: producers own a FIXED reservoir index r (W row in registers — zero
// LDS reads in steady state; x loads are wave-uniform L1 broadcasts), and
// ubuf uses a 16B-block XOR swizzle (m -> m ^ ((m>>3)&7)) making both the
// producer b32 writes and the consumer b128 reads bank-conflict-free.
//
// Consumer (wave 0) holds all 512 state elements in registers (8/lane,
// contiguous) and runs the serial recurrence with no per-step barrier;
// neighbor exchange is two __shfl lane rotations. Producers (waves 1-7)
// fill a double-buffered LDS u ring, 16 timesteps/phase, one lgkm-only
// barrier per phase (vmcnt NOT drained: consumer output stores stay in
// flight across barriers).

#define B_DIM 128
#define T_DIM 1024
#define D_DIM 8
#define R_DIM 512
#define NT    16            // timesteps per phase
#define NPHASE 64           // covers 1023 steps (last phase has 15)

#define SC   2.8853900817779268f   // 2*log2(e), folded into W and betas
#define BP_S (0.15f * SC)          // coeff on s[r+1], scaled
#define BM_S (0.85f * SC)          // coeff on s[r-1], scaled

__device__ __forceinline__ float esn_step(float L, float R, float u) {
    // pre' = 2log2e * (0.85 L + 0.15 R + u_raw); u already scaled.
    const float pre = fmaf(BM_S, L, fmaf(BP_S, R, u));
#if __has_builtin(__builtin_amdgcn_exp2f) && __has_builtin(__builtin_amdgcn_rcpf)
    const float e = __builtin_amdgcn_exp2f(pre);
    return fmaf(-2.0f, __builtin_amdgcn_rcpf(e + 1.0f), 1.0f);
#else
    const float e = exp2f(pre);
    return 1.0f - 2.0f / (e + 1.0f);
#endif
}

__device__ __forceinline__ void barrier_lds_only() {
    // LDS drain + barrier WITHOUT vmcnt(0): pending global stores (consumer)
    // stay in flight across the barrier.
    asm volatile("s_waitcnt lgkmcnt(0)\n\ts_barrier" ::: "memory");
}

// Byte offset of u element (tl, r) inside one ubuf buffer, with a 16B-block
// XOR swizzle: block m -> m ^ ((m>>3)&7). Bijective within each 128B group,
// preserves 16B alignment, and spreads the consumer's 32B-lane-stride reads
// across all 32 banks (8 accesses/bank = the 1024B/instr floor).
__device__ __forceinline__ int swz_byte(int tl, int r) {
    const int m = r >> 2;                       // 16B block index in row
    return tl * (R_DIM * 4) + ((m ^ ((m >> 3) & 7)) << 4) + ((r & 3) << 2);
}

__global__ __launch_bounds__(512, 1) void esn_kernel(const float* __restrict__ x,
                                                     const float* __restrict__ W,
                                                     float* __restrict__ out) {
    __shared__ float ubuf[2][NT][R_DIM];     // u ring, 64 KB (Wl removed)

    const int b   = blockIdx.x;
    const int tid = threadIdx.x;
    const float* xb = x + (size_t)b * T_DIM * D_DIM;
    char* ub0 = (char*)&ubuf[0][0][0];

    // ---- Own W row (scaled) in registers for the prologue.
    const float4 wa = *(const float4*)(W + tid * D_DIM);
    const float4 wc = *(const float4*)(W + tid * D_DIM + 4);
    const float w0 = wa.x * SC, w1 = wa.y * SC, w2 = wa.z * SC, w3 = wa.w * SC;
    const float w4 = wc.x * SC, w5 = wc.y * SC, w6 = wc.z * SC, w7 = wc.w * SC;

    // ---- Prologue: all 512 threads fill phase 0 (t = 1..16), r = tid.
    const int sb0 = swz_byte(0, tid);        // per-thread constant
#pragma unroll
    for (int j = 0; j < NT; ++j) {
        const float4 xa = *(const float4*)(xb + (j + 1) * D_DIM);
        const float4 xc = *(const float4*)(xb + (j + 1) * D_DIM + 4);
        float u = xa.x * w0;
        u = fmaf(xa.y, w1, u); u = fmaf(xa.z, w2, u); u = fmaf(xa.w, w3, u);
        u = fmaf(xc.x, w4, u); u = fmaf(xc.y, w5, u);
        u = fmaf(xc.z, w6, u); u = fmaf(xc.w, w7, u);
        *(float*)(ub0 + sb0 + j * (R_DIM * 4)) = u;
    }
    __syncthreads();  // one full barrier before the loop (no stores pending yet)

    const int wid  = tid >> 6;
    const int lane = tid & 63;

    if (wid == 0) {
        // ================= consumer =================
        asm volatile("s_setprio 3" ::: "memory");
        const int lp = (lane + 63) & 63;   // source of my left edge (s[7] of prev lane)
        const int ln = (lane + 1) & 63;    // source of my right edge (s[0] of next lane)
        // Swizzled byte offsets of my two 16B u blocks (constant per lane).
        const int o0 = ((2 * lane) ^ ((lane >> 2) & 7)) << 4;
        const int o1 = o0 ^ 16;

        float s[8];
#pragma unroll
        for (int e = 0; e < 8; ++e) s[e] = 0.0f;

        float* op = out + (size_t)b * T_DIM * R_DIM + lane * 8;

        for (int k = 0; k < NPHASE; ++k) {
            const char* ub = (const char*)&ubuf[k & 1][0][0];
            const int steps = (k == NPHASE - 1) ? (1023 - NT * (NPHASE - 1)) : NT;
            float4 ua = *(const float4*)(ub + o0);
            float4 uc = *(const float4*)(ub + o1);
            for (int tl = 0; tl < steps; ++tl) {
                // prefetch next step's u (off the critical path)
                const int tn = (tl + 1 < steps) ? (tl + 1) : tl;
                const float4 na = *(const float4*)(ub + tn * (R_DIM * 4) + o0);
                const float4 nc = *(const float4*)(ub + tn * (R_DIM * 4) + o1);

                const float L0 = __shfl(s[7], lp, 64);  // r-1 of my element 0
                const float R7 = __shfl(s[0], ln, 64);  // r+1 of my element 7

                // interior first: overlap the bpermute latency
                const float n1 = esn_step(s[0], s[2], ua.y);
                const float n2 = esn_step(s[1], s[3], ua.z);
                const float n3 = esn_step(s[2], s[4], ua.w);
                const float n4 = esn_step(s[3], s[5], uc.x);
                const float n5 = esn_step(s[4], s[6], uc.y);
                const float n6 = esn_step(s[5], s[7], uc.z);
                const float n0 = esn_step(L0,   s[1], ua.x);
                const float n7 = esn_step(s[6], R7,   uc.w);
                s[0] = n0; s[1] = n1; s[2] = n2; s[3] = n3;
                s[4] = n4; s[5] = n5; s[6] = n6; s[7] = n7;

                // fire-and-forget, coalesced 2 KB/wave
                *(float4*)(op)     = make_float4(n0, n1, n2, n3);
                *(float4*)(op + 4) = make_float4(n4, n5, n6, n7);
                op += R_DIM;

                ua = na; uc = nc;
            }
            barrier_lds_only();
        }
    } else {
        // ================= producers =================
        // Fixed r per thread: W row lives in registers, zero LDS reads in the
        // steady state. Wave 1 (pid 0..63) additionally owns r = pid + 448.
        asm volatile("s_setprio 0" ::: "memory");
        const int pid = tid - 64;  // 0..447
        const float4 pa = *(const float4*)(W + pid * D_DIM);
        const float4 pc = *(const float4*)(W + pid * D_DIM + 4);
        const float a0 = pa.x * SC, a1 = pa.y * SC, a2 = pa.z * SC, a3 = pa.w * SC;
        const float a4 = pc.x * SC, a5 = pc.y * SC, a6 = pc.z * SC, a7 = pc.w * SC;

        const bool dual = (wid == 1);   // pid < 64, wave-uniform
        float b0 = 0.f, b1 = 0.f, b2 = 0.f, b3 = 0.f,
              b4 = 0.f, b5 = 0.f, b6 = 0.f, b7 = 0.f;
        if (dual) {
            const float4 qa = *(const float4*)(W + (pid + 448) * D_DIM);
            const float4 qc = *(const float4*)(W + (pid + 448) * D_DIM + 4);
            b0 = qa.x * SC; b1 = qa.y * SC; b2 = qa.z * SC; b3 = qa.w * SC;
            b4 = qc.x * SC; b5 = qc.y * SC; b6 = qc.z * SC; b7 = qc.w * SC;
        }

        const int so_a = swz_byte(0, pid);          // per-thread constants
        const int so_b = swz_byte(0, pid + 448);

        for (int k = 0; k < NPHASE; ++k) {
            if (k + 1 < NPHASE) {
                const int tb = NT * (k + 1) + 1;      // first t of next phase
                char* dst = (char*)&ubuf[(k + 1) & 1][0][0];
#pragma unroll
                for (int tl = 0; tl < NT; ++tl) {
                    const int t = tb + tl;
                    if (t < T_DIM) {
                        // wave-uniform address: one 32B L1 line, broadcast
                        const float4 xa = *(const float4*)(xb + t * D_DIM);
                        const float4 xc = *(const float4*)(xb + t * D_DIM + 4);
                        float u = xa.x * a0;
                        u = fmaf(xa.y, a1, u); u = fmaf(xa.z, a2, u);
                        u = fmaf(xa.w, a3, u); u = fmaf(xc.x, a4, u);
                        u = fmaf(xc.y, a5, u); u = fmaf(xc.z, a6, u);
                        u = fmaf(xc.w, a7, u);
                        *(float*)(dst + so_a + tl * (R_DIM * 4)) = u;
                        if (dual) {
                            float u2 = xa.x * b0;
                            u2 = fmaf(xa.y, b1, u2); u2 = fmaf(xa.z, b2, u2);
                            u2 = fmaf(xa.w, b3, u2); u2 = fmaf(xc.x, b4, u2);
                            u2 = fmaf(xc.y, b5, u2); u2 = fmaf(xc.z, b6, u2);
                            u2 = fmaf(xc.w, b7, u2);
                            *(float*)(dst + so_b + tl * (R_DIM * 4)) = u2;
                        }
                    }
                }
            }
            barrier_lds_only();
        }
    }

    // Reference's final timestep is all zeros (d_out is poisoned 0xAA).
    out[(size_t)b * T_DIM * R_DIM + (size_t)(T_DIM - 1) * R_DIM + tid] = 0.0f;
}

extern "C" void kernel_launch(void* const* d_in, const int* in_sizes, int n_in,
                              void* d_out, int out_size, void* d_ws, size_t ws_size,
                              hipStream_t stream) {
    const float* x = (const float*)d_in[0];   // [B, T, D] fp32
    const float* W = (const float*)d_in[1];   // [R, D] fp32
    float* out = (float*)d_out;               // [B, T, R] fp32

    esn_kernel<<<dim3(B_DIM), dim3(512), 0, stream>>>(x, W, out);
}